// Round 14
// baseline (191.336 us; speedup 1.0000x reference)
//
#include <hip/hip_runtime.h>

// HierarchicalTimeAttention  B=4, T=4096, H=1024, D=4
// R14: gemm_o ported to R12's 907-TF structure: 256x128 tile, 8 waves 64x64,
// BK=64, 2 phases/tile, A(t+2) deep-stage into curA (R12-proven), counted
// vmcnt(4) at tile boundary. kvr (113.6us @ 38% MfmaUtil) unchanged.
// R13: 177us = kvr 113.6 + gemm_o 51(680TF, old R8 structure) + small 12.
#define B_ 4
#define T_ 4096
#define H_ 1024
#define D_ 4
#define M_ (B_ * T_)          // 16384
#define OUT_MAIN (M_ * H_)    // 16,777,216 (f32 elements)

// ws (bytes), total ~40.3MB:
#define WS_BUF  0UL           // bf16 [M][H]: o   (32MB)
#define WS_WK   33554432UL    // bf16 Wk,Wv,Wr,Wo contiguous [4][H][H] (8MB)
#define WS_LGW  41943040UL    // f32 softmax weights [M][4] (256KB)
#define WS_DEC  42205184UL    // f32 decayed_state0 [B][D][H] (64KB)

typedef __bf16 bf16x8 __attribute__((ext_vector_type(8)));
typedef unsigned short u16x4 __attribute__((ext_vector_type(4)));
typedef float f32x4 __attribute__((ext_vector_type(4)));

__device__ __forceinline__ float b2f(unsigned short u) {
    union { unsigned int i; float f; } c;
    c.i = ((unsigned int)u) << 16;
    return c.f;
}
__device__ __forceinline__ unsigned short f2b(float f) {
    union { float f; unsigned int i; } c;
    c.f = f;
    unsigned int x = c.i;
    unsigned int r = (x + 0x7FFFu + ((x >> 16) & 1u)) >> 16;  // RNE
    return (unsigned short)r;
}

#define BAR()  asm volatile("s_barrier" ::: "memory")
#define GLLDS(gsrc, ldst)                                                     \
    __builtin_amdgcn_global_load_lds(                                         \
        (const __attribute__((address_space(1))) unsigned int*)(gsrc),        \
        (__attribute__((address_space(3))) unsigned int*)(ldst), 16, 0, 0)

// ---------------------------------------------------------------------------
// 4 weight matrices -> bf16, one dispatch: grid (1024, 4), dst [4][H][H]
// ---------------------------------------------------------------------------
__global__ __launch_bounds__(256) void cvtw_k(
    const float* __restrict__ s0, const float* __restrict__ s1,
    const float* __restrict__ s2, const float* __restrict__ s3,
    unsigned short* __restrict__ d)
{
    const int w = blockIdx.y;
    const float* s = (w == 0) ? s0 : (w == 1) ? s1 : (w == 2) ? s2 : s3;
    const int i = blockIdx.x * 256 + threadIdx.x;
    const f32x4 v = ((const f32x4*)s)[i];
    u16x4 o;
    o[0] = f2b(v[0]); o[1] = f2b(v[1]); o[2] = f2b(v[2]); o[3] = f2b(v[3]);
    ((u16x4*)(d + (size_t)w * (H_ * H_)))[i] = o;
}

// ---------------------------------------------------------------------------
// logits + softmax + x->bf16 (fused): one wave per row.
// ---------------------------------------------------------------------------
__global__ __launch_bounds__(256) void logcvt_k(
    const float* __restrict__ X, const float* __restrict__ Wl,
    const float* __restrict__ bl, float* __restrict__ lgw,
    unsigned short* __restrict__ xb)
{
    const int wid  = threadIdx.x >> 6;
    const int lane = threadIdx.x & 63;
    const int row  = blockIdx.x * 4 + wid;
    const float* xp = X + (size_t)row * H_;
    unsigned short* xo = xb + (size_t)row * H_;

    float acc[D_] = {0.f, 0.f, 0.f, 0.f};
    for (int h = lane * 4; h < H_; h += 256) {
        const f32x4 xv = *(const f32x4*)(xp + h);
        u16x4 xc;
        xc[0] = f2b(xv[0]); xc[1] = f2b(xv[1]);
        xc[2] = f2b(xv[2]); xc[3] = f2b(xv[3]);
        *(u16x4*)(xo + h) = xc;
#pragma unroll
        for (int d = 0; d < D_; ++d) {
            const f32x4 wv = *(const f32x4*)(Wl + d * H_ + h);
            acc[d] += xv[0] * wv[0] + xv[1] * wv[1] + xv[2] * wv[2] + xv[3] * wv[3];
        }
    }
#pragma unroll
    for (int off = 32; off; off >>= 1)
#pragma unroll
        for (int d = 0; d < D_; ++d) acc[d] += __shfl_xor(acc[d], off, 64);

    if (lane == 0) {
        float l[D_];
#pragma unroll
        for (int d = 0; d < D_; ++d) l[d] = acc[d] + bl[d];
        const float mx = fmaxf(fmaxf(l[0], l[1]), fmaxf(l[2], l[3]));
        float e[D_], s = 0.f;
#pragma unroll
        for (int d = 0; d < D_; ++d) { e[d] = __expf(l[d] - mx); s += e[d]; }
        const float inv = 1.0f / s;
        f32x4 o;
#pragma unroll
        for (int d = 0; d < D_; ++d) o[d] = e[d] * inv;
        *(f32x4*)(lgw + (size_t)row * 4) = o;
    }
}

// ---------------------------------------------------------------------------
__global__ void decstate_k(const float* __restrict__ state,
                           const float* __restrict__ tdm,
                           float* __restrict__ dec)
{
    const int i = blockIdx.x * blockDim.x + threadIdx.x;
    if (i >= B_ * D_ * H_) return;
    const int dh = i & (D_ * H_ - 1);
    dec[i] = state[i] * __expf(-__expf(tdm[dh]));
}

// ---------------------------------------------------------------------------
// new_state[b,d,h] = dec[b,d,h] + k_last*v_last, all-f32 exact path.
// ---------------------------------------------------------------------------
__global__ __launch_bounds__(256) void newstate_k(
    const float* __restrict__ X, const float* __restrict__ Wk,
    const float* __restrict__ Wv, const float* __restrict__ dec,
    float* __restrict__ out2)
{
    const int wid  = threadIdx.x >> 6;
    const int lane = threadIdx.x & 63;
    const int row  = blockIdx.x * 4 + wid;   // 0..B*H-1
    const int b    = row >> 10;
    const int h    = row & (H_ - 1);
    const float* xp = X + ((size_t)(b * T_ + (T_ - 1))) * H_;

    float ak = 0.f, av = 0.f;
    for (int j = lane * 4; j < H_; j += 256) {
        const f32x4 xv = *(const f32x4*)(xp + j);
        const f32x4 wk = *(const f32x4*)(Wk + (size_t)h * H_ + j);
        const f32x4 wv = *(const f32x4*)(Wv + (size_t)h * H_ + j);
        ak += xv[0]*wk[0] + xv[1]*wk[1] + xv[2]*wk[2] + xv[3]*wk[3];
        av += xv[0]*wv[0] + xv[1]*wv[1] + xv[2]*wv[2] + xv[3]*wv[3];
    }
#pragma unroll
    for (int off = 32; off; off >>= 1) {
        ak += __shfl_xor(ak, off, 64);
        av += __shfl_xor(av, off, 64);
    }
    if (lane == 0) {
        const float kv = ak * av;
#pragma unroll
        for (int d = 0; d < D_; ++d)
            out2[(size_t)(b * D_ + d) * H_ + h] = dec[(b * D_ + d) * H_ + h] + kv;
    }
}

// ---------------------------------------------------------------------------
// FUSED KVR GEMM + o-epilogue (R13 verbatim, 113.6us @ 38% MfmaUtil).
// ---------------------------------------------------------------------------
__global__ __launch_bounds__(512, 2) void gemm_kvr(
    const unsigned short* __restrict__ A,
    const unsigned short* __restrict__ Wk,
    const unsigned short* __restrict__ Wv,
    const unsigned short* __restrict__ Wr,
    unsigned short* __restrict__ Co,
    const float* __restrict__ lgw,
    const float* __restrict__ dec)
{
    __shared__ __align__(16) unsigned short As [2 * 8192];   // [2][128][64]
    __shared__ __align__(16) unsigned short Bks[2 * 8192];
    __shared__ __align__(16) unsigned short Bvs[2 * 8192];
    __shared__ __align__(16) unsigned short Brs[2 * 8192];

    const int tid  = threadIdx.x;
    const int wid  = tid >> 6;
    const int lane = tid & 63;
    const int l15  = lane & 15;
    const int q    = lane >> 4;
    const int wrow = wid >> 2;        // 0..1
    const int wcol = wid & 3;         // 0..3
    const int bcol = blockIdx.x * 128;
    const int brow = blockIdx.y * 128;

    const int g0row = tid >> 3, g0cg = (tid & 7) ^ (g0row & 7);
    const int g1row = 64 + g0row, g1cg = (tid & 7) ^ (g1row & 7);
    const int offA0 = (brow + g0row) * 1024 + g0cg * 8;
    const int offA1 = (brow + g1row) * 1024 + g1cg * 8;
    const int offB0 = (bcol + g0row) * 1024 + g0cg * 8;
    const int offB1 = (bcol + g1row) * 1024 + g1cg * 8;
    const int dst0 = tid * 8;
    const int dst1 = 4096 + tid * 8;

    int gx[2];
#pragma unroll
    for (int ks = 0; ks < 2; ++ks) gx[ks] = ((ks * 4 + q) ^ (l15 & 7)) * 8;
    int aB[4], bB[2];
#pragma unroll
    for (int mi = 0; mi < 4; ++mi) aB[mi] = (wrow * 64 + mi * 16 + l15) * 64;
#pragma unroll
    for (int ni = 0; ni < 2; ++ni) bB[ni] = (wcol * 32 + ni * 16 + l15) * 64;

    f32x4 accK[4][2], accV[4][2], accR[4][2];
#pragma unroll
    for (int i = 0; i < 4; ++i)
#pragma unroll
        for (int j = 0; j < 2; ++j) {
            accK[i][j] = (f32x4){0.f, 0.f, 0.f, 0.f};
            accV[i][j] = (f32x4){0.f, 0.f, 0.f, 0.f};
            accR[i][j] = (f32x4){0.f, 0.f, 0.f, 0.f};
        }

#define SG_A(bo, tau)  do { GLLDS(A  + offA0 + (tau) * 64, As  + (bo) + dst0); \
                            GLLDS(A  + offA1 + (tau) * 64, As  + (bo) + dst1); } while (0)
#define SG_BK(bo, tau) do { GLLDS(Wk + offB0 + (tau) * 64, Bks + (bo) + dst0); \
                            GLLDS(Wk + offB1 + (tau) * 64, Bks + (bo) + dst1); } while (0)
#define SG_BV(bo, tau) do { GLLDS(Wv + offB0 + (tau) * 64, Bvs + (bo) + dst0); \
                            GLLDS(Wv + offB1 + (tau) * 64, Bvs + (bo) + dst1); } while (0)
#define SG_BR(bo, tau) do { GLLDS(Wr + offB0 + (tau) * 64, Brs + (bo) + dst0); \
                            GLLDS(Wr + offB1 + (tau) * 64, Brs + (bo) + dst1); } while (0)
#define RD_AALL(CUR)                                                          \
    _Pragma("unroll") for (int mi = 0; mi < 4; ++mi)                          \
    _Pragma("unroll") for (int ks = 0; ks < 2; ++ks)                          \
        aR[mi][ks] = *(const bf16x8*)&As[(CUR) + aB[mi] + gx[ks]];
#define RD_B(ARR, CUR)                                                        \
    _Pragma("unroll") for (int nj = 0; nj < 2; ++nj)                          \
    _Pragma("unroll") for (int ks = 0; ks < 2; ++ks)                          \
        bR[nj][ks] = *(const bf16x8*)&ARR[(CUR) + bB[nj] + gx[ks]];
#define MFMA16(ACC)                                                           \
    __builtin_amdgcn_s_setprio(1);                                            \
    _Pragma("unroll") for (int mi = 0; mi < 4; ++mi)                          \
    _Pragma("unroll") for (int nj = 0; nj < 2; ++nj)                          \
    _Pragma("unroll") for (int ks = 0; ks < 2; ++ks)                          \
        ACC[mi][nj] = __builtin_amdgcn_mfma_f32_16x16x32_bf16(                \
            aR[mi][ks], bR[nj][ks], ACC[mi][nj], 0, 0, 0);                    \
    __builtin_amdgcn_s_setprio(0);

    SG_A(0, 0); SG_BK(0, 0); SG_BV(0, 0); SG_BR(0, 0);
    asm volatile("s_waitcnt vmcnt(4)" ::: "memory");
    BAR();

#pragma unroll 1
    for (int t = 0; t < 15; ++t) {
        const int cur = (t & 1) << 13;
        const int nxt = cur ^ 8192;
        bf16x8 aR[4][2], bR[2][2];

        RD_AALL(cur); RD_B(Bks, cur);
        SG_A(nxt, t + 1); SG_BK(nxt, t + 1);
        BAR(); MFMA16(accK);
        asm volatile("s_waitcnt vmcnt(6)" ::: "memory");
        BAR();

        RD_B(Bvs, cur);
        SG_BV(nxt, t + 1);
        BAR(); MFMA16(accV);
        asm volatile("s_waitcnt vmcnt(6)" ::: "memory");
        BAR();

        RD_B(Brs, cur);
        SG_BR(nxt, t + 1);
        BAR(); MFMA16(accR);
        asm volatile("s_waitcnt vmcnt(4)" ::: "memory");
        BAR();
    }
    {
        const int cur = 8192;
        bf16x8 aR[4][2], bR[2][2];
        RD_AALL(cur); RD_B(Bks, cur);
        BAR(); MFMA16(accK);
        asm volatile("s_waitcnt vmcnt(2)" ::: "memory");
        BAR();
        RD_B(Bvs, cur);
        BAR(); MFMA16(accV);
        asm volatile("s_waitcnt vmcnt(0)" ::: "memory");
        BAR();
        RD_B(Brs, cur);
        MFMA16(accR);
    }
#undef SG_A
#undef SG_BK
#undef SG_BV
#undef SG_BR
#undef RD_AALL
#undef RD_B
#undef MFMA16

    const int orow0 = brow + wrow * 64;
    const int ocol0 = bcol + wcol * 32;
    const int rbase = q * 4;
    const int b = brow >> 12;
    float dcol[2][4];
#pragma unroll
    for (int ni = 0; ni < 2; ++ni)
#pragma unroll
        for (int d = 0; d < 4; ++d)
            dcol[ni][d] = dec[b * (D_ * H_) + d * H_ + (ocol0 + ni * 16 + l15)];
#pragma unroll
    for (int mi = 0; mi < 4; ++mi)
#pragma unroll
        for (int j = 0; j < 4; ++j) {
            const int r = orow0 + mi * 16 + rbase + j;
            const f32x4 lw = *(const f32x4*)(lgw + (size_t)r * 4);
            const float wsum = lw[0] + lw[1] + lw[2] + lw[3];
#pragma unroll
            for (int ni = 0; ni < 2; ++ni) {
                const size_t idx = (size_t)r * 1024 + (ocol0 + ni * 16 + l15);
                const float kvf = b2f(f2b(accV[mi][ni][j] * b2f(f2b(accK[mi][ni][j]))));
                const float rv  = 1.0f / (1.0f + __expf(-accR[mi][ni][j]));
                const float w   = lw[0] * dcol[ni][0] + lw[1] * dcol[ni][1]
                                + lw[2] * dcol[ni][2] + lw[3] * dcol[ni][3]
                                + wsum * kvf;
                Co[idx] = f2b(rv * w);
            }
        }
}

// ---------------------------------------------------------------------------
// o-GEMM, R12-structure port: out = f32(o @ Wo^T)
// 256x128 tile, 8 waves (4Mx2N, 64x64/wave), BK=64. LDS: A 2x32KB + B 2x16KB.
// 2 phases/tile:
//   P1: rd a(8)+b(n01,4); stage B(t+1)[2]; BAR; MFMA n01(16); BAR
//   P2: rd b(n23,4); stage A(t+2)[4] into curA (legal: P1 MFMA consumed all
//       a-reads before any wave passed P1's barriers); BAR; MFMA n23(16);
//       vmcnt(4) [FIFO: drains B(t+1), leaves A(t+2) in flight]; BAR
// Never vmcnt(0) in main loop. Same swizzle/frag maps as R12 (conflicts=0).
// Per-element MFMA order identical to R13's gemm_o -> absmax bit-identical.
// ---------------------------------------------------------------------------
__global__ __launch_bounds__(512, 2) void gemm_o2(
    const unsigned short* __restrict__ A,
    const unsigned short* __restrict__ Wt,
    float* __restrict__ outf)
{
    __shared__ __align__(16) unsigned short As[2 * 16384];   // [2][256][64]
    __shared__ __align__(16) unsigned short Bs[2 * 8192];    // [2][128][64]

    const int tid  = threadIdx.x;
    const int wid  = tid >> 6;        // 0..7
    const int lane = tid & 63;
    const int l15  = lane & 15;
    const int q    = lane >> 4;
    const int wrow = wid >> 1;        // 0..3 (64-row quarter)
    const int wcol = wid & 1;         // 0..1 (64-col half)
    const int brow = blockIdx.x * 256;
    const int bcol = blockIdx.y * 128;

    // staging: A = 4 calls (rows 0-255), B = 2 calls (rows 0-127)
    int offA[4], dstA[4];
#pragma unroll
    for (int i = 0; i < 4; ++i) {
        const int G   = i * 512 + tid;
        const int row = G >> 3;
        const int cg  = (G & 7) ^ (row & 7);
        offA[i] = (brow + row) * 1024 + cg * 8;
        dstA[i] = G * 8;
    }
    int offB[2], dstB[2];
#pragma unroll
    for (int j = 0; j < 2; ++j) {
        const int G   = j * 512 + tid;
        const int row = G >> 3;
        const int cg  = (G & 7) ^ (row & 7);
        offB[j] = (bcol + row) * 1024 + cg * 8;
        dstB[j] = G * 8;
    }

    int gx[2];
#pragma unroll
    for (int ks = 0; ks < 2; ++ks) gx[ks] = ((ks * 4 + q) ^ (l15 & 7)) * 8;
    int aB[4], bB[4];
#pragma unroll
    for (int mi = 0; mi < 4; ++mi) aB[mi] = (wrow * 64 + mi * 16 + l15) * 64;
#pragma unroll
    for (int ni = 0; ni < 4; ++ni) bB[ni] = (wcol * 64 + ni * 16 + l15) * 64;

    f32x4 acc[4][4];
#pragma unroll
    for (int i = 0; i < 4; ++i)
#pragma unroll
        for (int j = 0; j < 4; ++j)
            acc[i][j] = (f32x4){0.f, 0.f, 0.f, 0.f};

#define SG_A(bo, tau)  do { GLLDS(A + offA[0] + (tau) * 64, As + (bo) + dstA[0]); \
                            GLLDS(A + offA[1] + (tau) * 64, As + (bo) + dstA[1]); \
                            GLLDS(A + offA[2] + (tau) * 64, As + (bo) + dstA[2]); \
                            GLLDS(A + offA[3] + (tau) * 64, As + (bo) + dstA[3]); } while (0)
#define SG_B(bo, tau)  do { GLLDS(Wt + offB[0] + (tau) * 64, Bs + (bo) + dstB[0]); \
                            GLLDS(Wt + offB[1] + (tau) * 64, Bs + (bo) + dstB[1]); } while (0)
#define RD_AALL(CUR)                                                          \
    _Pragma("unroll") for (int mi = 0; mi < 4; ++mi)                          \
    _Pragma("unroll") for (int ks = 0; ks < 2; ++ks)                          \
        aR[mi][ks] = *(const bf16x8*)&As[(CUR) + aB[mi] + gx[ks]];
#define RD_B2(CUR, N0)                                                        \
    _Pragma("unroll") for (int nj = 0; nj < 2; ++nj)                          \
    _Pragma("unroll") for (int ks = 0; ks < 2; ++ks)                          \
        bR[nj][ks] = *(const bf16x8*)&Bs[(CUR) + bB[(N0) + nj] + gx[ks]];
#define MFMA16(N0)                                                            \
    __builtin_amdgcn_s_setprio(1);                                            \
    _Pragma("unroll") for (int mi = 0; mi < 4; ++mi)                          \
    _Pragma("unroll") for (int nj = 0; nj < 2; ++nj)                          \
    _Pragma("unroll") for (int ks = 0; ks < 2; ++ks)                          \
        acc[mi][(N0) + nj] = __builtin_amdgcn_mfma_f32_16x16x32_bf16(         \
            aR[mi][ks], bR[nj][ks], acc[mi][(N0) + nj], 0, 0, 0);             \
    __builtin_amdgcn_s_setprio(0);

    // prologue: A(0), B(0), A(1); drain A(0),B(0), leave A(1) in flight
    SG_A(0, 0); SG_B(0, 0); SG_A(16384, 1);
    asm volatile("s_waitcnt vmcnt(4)" ::: "memory");
    BAR();

#pragma unroll 1
    for (int t = 0; t < 15; ++t) {
        const int curA = (t & 1) << 14;
        const int curB = (t & 1) << 13;
        const int nxtB = curB ^ 8192;
        bf16x8 aR[4][2], bR[2][2];

        // P1: all a-reads + b(n01); stage B(t+1)
        RD_AALL(curA); RD_B2(curB, 0);
        SG_B(nxtB, t + 1);
        BAR(); MFMA16(0); BAR();

        // P2: b(n23); stage A(t+2) into curA (a-reads certified done)
        RD_B2(curB, 2);
        if (t < 14) SG_A(curA, t + 2);
        BAR(); MFMA16(2);
        if (t < 14) asm volatile("s_waitcnt vmcnt(4)" ::: "memory");
        else        asm volatile("s_waitcnt vmcnt(0)" ::: "memory");
        BAR();
    }
    // tail: tile 15 fully resident
    {
        const int curA = 16384, curB = 8192;
        bf16x8 aR[4][2], bR[2][2];
        RD_AALL(curA);
        RD_B2(curB, 0); MFMA16(0);
        RD_B2(curB, 2); MFMA16(2);
    }
#undef SG_A
#undef SG_B
#undef RD_AALL
#undef RD_B2
#undef MFMA16

    const int orow0 = brow + wrow * 64;
    const int ocol0 = bcol + wcol * 64;
    const int rbase = q * 4;
#pragma unroll
    for (int mi = 0; mi < 4; ++mi)
#pragma unroll
        for (int j = 0; j < 4; ++j) {
            const size_t r = (size_t)(orow0 + mi * 16 + rbase + j);
#pragma unroll
            for (int ni = 0; ni < 4; ++ni)
                outf[r * 1024 + (ocol0 + ni * 16 + l15)] = acc[mi][ni][j];
        }
}

// ---------------------------------------------------------------------------
extern "C" void kernel_launch(void* const* d_in, const int* in_sizes, int n_in,
                              void* d_out, int out_size, void* d_ws, size_t ws_size,
                              hipStream_t stream)
{
    const float* x   = (const float*)d_in[0];
    const float* st  = (const float*)d_in[1];
    const float* tdm = (const float*)d_in[2];
    const float* Wl  = (const float*)d_in[3];
    const float* bl  = (const float*)d_in[4];
    const float* Wv  = (const float*)d_in[5];
    const float* Wk  = (const float*)d_in[6];
    const float* Wr  = (const float*)d_in[7];
    const float* Wo  = (const float*)d_in[8];
    float* out = (float*)d_out;                    // f32 output

    char* ws = (char*)d_ws;
    unsigned short* buf  = (unsigned short*)(ws + WS_BUF);   // o
    unsigned short* wk_b = (unsigned short*)(ws + WS_WK);    // [4][H][H]: k,v,r,o
    unsigned short* wv_b = wk_b + 1 * (H_ * H_);
    unsigned short* wr_b = wk_b + 2 * (H_ * H_);
    unsigned short* wo_b = wk_b + 3 * (H_ * H_);
    float* lgw = (float*)(ws + WS_LGW);
    float* dec = (float*)(ws + WS_DEC);

    // bf16 x scratch inside d_out's f32 output-0 region; final GEMM
    // fully overwrites it afterwards.
    unsigned short* xb = (unsigned short*)out;

    // small kernels
    decstate_k<<<(B_ * D_ * H_ + 255) / 256, 256, 0, stream>>>(st, tdm, dec);
    logcvt_k<<<M_ / 4, 256, 0, stream>>>(x, Wl, bl, lgw, xb);
    newstate_k<<<(B_ * H_) / 4, 256, 0, stream>>>(x, Wk, Wv, dec, out + OUT_MAIN);
    cvtw_k<<<dim3(1024, 4), 256, 0, stream>>>(Wk, Wv, Wr, Wo, wk_b);

    // buf = o = sigmoid(x@Wr^T) * (lw.dec + wsum*(x@Wk^T * x@Wv^T))
    gemm_kvr<<<dim3(H_ / 128, M_ / 128), 512, 0, stream>>>(
        xb, wk_b, wv_b, wr_b, buf, lgw, dec);

    // out = f32(o @ Wo^T)  [R12-structure]
    gemm_o2<<<dim3(M_ / 256, H_ / 128), 512, 0, stream>>>(buf, wo_b, out);
}

// Round 15
// 175.377 us; speedup vs baseline: 1.0910x; 1.0910x over previous
//
#include <hip/hip_runtime.h>

// HierarchicalTimeAttention  B=4, T=4096, H=1024, D=4
// R15: revert gemm_o to R13's R8-structure (R14's 256x128 port regressed
// 51->65us: fusion was the R12 win, not the schedule). Add XCD-aware block
// swizzle to gemm_kvr: old mapping put the 8 A-panel-sharing blocks on 8
// DIFFERENT XCDs (FETCH 144.5MB, ~4x A over-fetch); new bijective map gives
// each XCD 16 full row-bands -> A-panel fetched into one L2 only.
// R13 baseline: 177us = kvr 113.6 (38% MfmaUtil) + gemm_o 51 + small 12.
#define B_ 4
#define T_ 4096
#define H_ 1024
#define D_ 4
#define M_ (B_ * T_)          // 16384
#define OUT_MAIN (M_ * H_)    // 16,777,216 (f32 elements)

// ws (bytes), total ~40.3MB:
#define WS_BUF  0UL           // bf16 [M][H]: o   (32MB)
#define WS_WK   33554432UL    // bf16 Wk,Wv,Wr,Wo contiguous [4][H][H] (8MB)
#define WS_LGW  41943040UL    // f32 softmax weights [M][4] (256KB)
#define WS_DEC  42205184UL    // f32 decayed_state0 [B][D][H] (64KB)

typedef __bf16 bf16x8 __attribute__((ext_vector_type(8)));
typedef unsigned short u16x4 __attribute__((ext_vector_type(4)));
typedef float f32x4 __attribute__((ext_vector_type(4)));

__device__ __forceinline__ float b2f(unsigned short u) {
    union { unsigned int i; float f; } c;
    c.i = ((unsigned int)u) << 16;
    return c.f;
}
__device__ __forceinline__ unsigned short f2b(float f) {
    union { float f; unsigned int i; } c;
    c.f = f;
    unsigned int x = c.i;
    unsigned int r = (x + 0x7FFFu + ((x >> 16) & 1u)) >> 16;  // RNE
    return (unsigned short)r;
}

#define BAR()  asm volatile("s_barrier" ::: "memory")
#define GLLDS(gsrc, ldst)                                                     \
    __builtin_amdgcn_global_load_lds(                                         \
        (const __attribute__((address_space(1))) unsigned int*)(gsrc),        \
        (__attribute__((address_space(3))) unsigned int*)(ldst), 16, 0, 0)

// ---------------------------------------------------------------------------
// 4 weight matrices -> bf16, one dispatch: grid (1024, 4), dst [4][H][H]
// ---------------------------------------------------------------------------
__global__ __launch_bounds__(256) void cvtw_k(
    const float* __restrict__ s0, const float* __restrict__ s1,
    const float* __restrict__ s2, const float* __restrict__ s3,
    unsigned short* __restrict__ d)
{
    const int w = blockIdx.y;
    const float* s = (w == 0) ? s0 : (w == 1) ? s1 : (w == 2) ? s2 : s3;
    const int i = blockIdx.x * 256 + threadIdx.x;
    const f32x4 v = ((const f32x4*)s)[i];
    u16x4 o;
    o[0] = f2b(v[0]); o[1] = f2b(v[1]); o[2] = f2b(v[2]); o[3] = f2b(v[3]);
    ((u16x4*)(d + (size_t)w * (H_ * H_)))[i] = o;
}

// ---------------------------------------------------------------------------
// logits + softmax + x->bf16 (fused): one wave per row.
// ---------------------------------------------------------------------------
__global__ __launch_bounds__(256) void logcvt_k(
    const float* __restrict__ X, const float* __restrict__ Wl,
    const float* __restrict__ bl, float* __restrict__ lgw,
    unsigned short* __restrict__ xb)
{
    const int wid  = threadIdx.x >> 6;
    const int lane = threadIdx.x & 63;
    const int row  = blockIdx.x * 4 + wid;
    const float* xp = X + (size_t)row * H_;
    unsigned short* xo = xb + (size_t)row * H_;

    float acc[D_] = {0.f, 0.f, 0.f, 0.f};
    for (int h = lane * 4; h < H_; h += 256) {
        const f32x4 xv = *(const f32x4*)(xp + h);
        u16x4 xc;
        xc[0] = f2b(xv[0]); xc[1] = f2b(xv[1]);
        xc[2] = f2b(xv[2]); xc[3] = f2b(xv[3]);
        *(u16x4*)(xo + h) = xc;
#pragma unroll
        for (int d = 0; d < D_; ++d) {
            const f32x4 wv = *(const f32x4*)(Wl + d * H_ + h);
            acc[d] += xv[0] * wv[0] + xv[1] * wv[1] + xv[2] * wv[2] + xv[3] * wv[3];
        }
    }
#pragma unroll
    for (int off = 32; off; off >>= 1)
#pragma unroll
        for (int d = 0; d < D_; ++d) acc[d] += __shfl_xor(acc[d], off, 64);

    if (lane == 0) {
        float l[D_];
#pragma unroll
        for (int d = 0; d < D_; ++d) l[d] = acc[d] + bl[d];
        const float mx = fmaxf(fmaxf(l[0], l[1]), fmaxf(l[2], l[3]));
        float e[D_], s = 0.f;
#pragma unroll
        for (int d = 0; d < D_; ++d) { e[d] = __expf(l[d] - mx); s += e[d]; }
        const float inv = 1.0f / s;
        f32x4 o;
#pragma unroll
        for (int d = 0; d < D_; ++d) o[d] = e[d] * inv;
        *(f32x4*)(lgw + (size_t)row * 4) = o;
    }
}

// ---------------------------------------------------------------------------
__global__ void decstate_k(const float* __restrict__ state,
                           const float* __restrict__ tdm,
                           float* __restrict__ dec)
{
    const int i = blockIdx.x * blockDim.x + threadIdx.x;
    if (i >= B_ * D_ * H_) return;
    const int dh = i & (D_ * H_ - 1);
    dec[i] = state[i] * __expf(-__expf(tdm[dh]));
}

// ---------------------------------------------------------------------------
// new_state[b,d,h] = dec[b,d,h] + k_last*v_last, all-f32 exact path.
// ---------------------------------------------------------------------------
__global__ __launch_bounds__(256) void newstate_k(
    const float* __restrict__ X, const float* __restrict__ Wk,
    const float* __restrict__ Wv, const float* __restrict__ dec,
    float* __restrict__ out2)
{
    const int wid  = threadIdx.x >> 6;
    const int lane = threadIdx.x & 63;
    const int row  = blockIdx.x * 4 + wid;   // 0..B*H-1
    const int b    = row >> 10;
    const int h    = row & (H_ - 1);
    const float* xp = X + ((size_t)(b * T_ + (T_ - 1))) * H_;

    float ak = 0.f, av = 0.f;
    for (int j = lane * 4; j < H_; j += 256) {
        const f32x4 xv = *(const f32x4*)(xp + j);
        const f32x4 wk = *(const f32x4*)(Wk + (size_t)h * H_ + j);
        const f32x4 wv = *(const f32x4*)(Wv + (size_t)h * H_ + j);
        ak += xv[0]*wk[0] + xv[1]*wk[1] + xv[2]*wk[2] + xv[3]*wk[3];
        av += xv[0]*wv[0] + xv[1]*wv[1] + xv[2]*wv[2] + xv[3]*wv[3];
    }
#pragma unroll
    for (int off = 32; off; off >>= 1) {
        ak += __shfl_xor(ak, off, 64);
        av += __shfl_xor(av, off, 64);
    }
    if (lane == 0) {
        const float kv = ak * av;
#pragma unroll
        for (int d = 0; d < D_; ++d)
            out2[(size_t)(b * D_ + d) * H_ + h] = dec[(b * D_ + d) * H_ + h] + kv;
    }
}

// ---------------------------------------------------------------------------
// FUSED KVR GEMM + o-epilogue (R13 structure) + XCD-aware block swizzle.
// Grid (8, 128) linear id lin = y*8+x; hw XCD = lin%8. New map: each XCD
// owns 16 contiguous brow-bands (all 8 bcols) -> A-panel lands in ONE L2.
// Bijective (1024 = 8*128). All else identical to R13 (113.6us, 38% Mfma).
// ---------------------------------------------------------------------------
__global__ __launch_bounds__(512, 2) void gemm_kvr(
    const unsigned short* __restrict__ A,
    const unsigned short* __restrict__ Wk,
    const unsigned short* __restrict__ Wv,
    const unsigned short* __restrict__ Wr,
    unsigned short* __restrict__ Co,
    const float* __restrict__ lgw,
    const float* __restrict__ dec)
{
    __shared__ __align__(16) unsigned short As [2 * 8192];   // [2][128][64]
    __shared__ __align__(16) unsigned short Bks[2 * 8192];
    __shared__ __align__(16) unsigned short Bvs[2 * 8192];
    __shared__ __align__(16) unsigned short Brs[2 * 8192];

    const int tid  = threadIdx.x;
    const int wid  = tid >> 6;
    const int lane = tid & 63;
    const int l15  = lane & 15;
    const int q    = lane >> 4;
    const int wrow = wid >> 2;        // 0..1
    const int wcol = wid & 3;         // 0..3

    // XCD-aware swizzle (T1): lin -> (xcd, slot); xcd owns brows [16x,16x+16)
    const int lin  = blockIdx.y * 8 + blockIdx.x;
    const int xcd  = lin & 7;
    const int slot = lin >> 3;                // 0..127
    const int brow = (xcd * 16 + (slot >> 3)) * 128;
    const int bcol = (slot & 7) * 128;

    const int g0row = tid >> 3, g0cg = (tid & 7) ^ (g0row & 7);
    const int g1row = 64 + g0row, g1cg = (tid & 7) ^ (g1row & 7);
    const int offA0 = (brow + g0row) * 1024 + g0cg * 8;
    const int offA1 = (brow + g1row) * 1024 + g1cg * 8;
    const int offB0 = (bcol + g0row) * 1024 + g0cg * 8;
    const int offB1 = (bcol + g1row) * 1024 + g1cg * 8;
    const int dst0 = tid * 8;
    const int dst1 = 4096 + tid * 8;

    int gx[2];
#pragma unroll
    for (int ks = 0; ks < 2; ++ks) gx[ks] = ((ks * 4 + q) ^ (l15 & 7)) * 8;
    int aB[4], bB[2];
#pragma unroll
    for (int mi = 0; mi < 4; ++mi) aB[mi] = (wrow * 64 + mi * 16 + l15) * 64;
#pragma unroll
    for (int ni = 0; ni < 2; ++ni) bB[ni] = (wcol * 32 + ni * 16 + l15) * 64;

    f32x4 accK[4][2], accV[4][2], accR[4][2];
#pragma unroll
    for (int i = 0; i < 4; ++i)
#pragma unroll
        for (int j = 0; j < 2; ++j) {
            accK[i][j] = (f32x4){0.f, 0.f, 0.f, 0.f};
            accV[i][j] = (f32x4){0.f, 0.f, 0.f, 0.f};
            accR[i][j] = (f32x4){0.f, 0.f, 0.f, 0.f};
        }

#define SG_A(bo, tau)  do { GLLDS(A  + offA0 + (tau) * 64, As  + (bo) + dst0); \
                            GLLDS(A  + offA1 + (tau) * 64, As  + (bo) + dst1); } while (0)
#define SG_BK(bo, tau) do { GLLDS(Wk + offB0 + (tau) * 64, Bks + (bo) + dst0); \
                            GLLDS(Wk + offB1 + (tau) * 64, Bks + (bo) + dst1); } while (0)
#define SG_BV(bo, tau) do { GLLDS(Wv + offB0 + (tau) * 64, Bvs + (bo) + dst0); \
                            GLLDS(Wv + offB1 + (tau) * 64, Bvs + (bo) + dst1); } while (0)
#define SG_BR(bo, tau) do { GLLDS(Wr + offB0 + (tau) * 64, Brs + (bo) + dst0); \
                            GLLDS(Wr + offB1 + (tau) * 64, Brs + (bo) + dst1); } while (0)
#define RD_AALL(CUR)                                                          \
    _Pragma("unroll") for (int mi = 0; mi < 4; ++mi)                          \
    _Pragma("unroll") for (int ks = 0; ks < 2; ++ks)                          \
        aR[mi][ks] = *(const bf16x8*)&As[(CUR) + aB[mi] + gx[ks]];
#define RD_B(ARR, CUR)                                                        \
    _Pragma("unroll") for (int nj = 0; nj < 2; ++nj)                          \
    _Pragma("unroll") for (int ks = 0; ks < 2; ++ks)                          \
        bR[nj][ks] = *(const bf16x8*)&ARR[(CUR) + bB[nj] + gx[ks]];
#define MFMA16(ACC)                                                           \
    __builtin_amdgcn_s_setprio(1);                                            \
    _Pragma("unroll") for (int mi = 0; mi < 4; ++mi)                          \
    _Pragma("unroll") for (int nj = 0; nj < 2; ++nj)                          \
    _Pragma("unroll") for (int ks = 0; ks < 2; ++ks)                          \
        ACC[mi][nj] = __builtin_amdgcn_mfma_f32_16x16x32_bf16(                \
            aR[mi][ks], bR[nj][ks], ACC[mi][nj], 0, 0, 0);                    \
    __builtin_amdgcn_s_setprio(0);

    SG_A(0, 0); SG_BK(0, 0); SG_BV(0, 0); SG_BR(0, 0);
    asm volatile("s_waitcnt vmcnt(4)" ::: "memory");
    BAR();

#pragma unroll 1
    for (int t = 0; t < 15; ++t) {
        const int cur = (t & 1) << 13;
        const int nxt = cur ^ 8192;
        bf16x8 aR[4][2], bR[2][2];

        RD_AALL(cur); RD_B(Bks, cur);
        SG_A(nxt, t + 1); SG_BK(nxt, t + 1);
        BAR(); MFMA16(accK);
        asm volatile("s_waitcnt vmcnt(6)" ::: "memory");
        BAR();

        RD_B(Bvs, cur);
        SG_BV(nxt, t + 1);
        BAR(); MFMA16(accV);
        asm volatile("s_waitcnt vmcnt(6)" ::: "memory");
        BAR();

        RD_B(Brs, cur);
        SG_BR(nxt, t + 1);
        BAR(); MFMA16(accR);
        asm volatile("s_waitcnt vmcnt(4)" ::: "memory");
        BAR();
    }
    {
        const int cur = 8192;
        bf16x8 aR[4][2], bR[2][2];
        RD_AALL(cur); RD_B(Bks, cur);
        BAR(); MFMA16(accK);
        asm volatile("s_waitcnt vmcnt(2)" ::: "memory");
        BAR();
        RD_B(Bvs, cur);
        BAR(); MFMA16(accV);
        asm volatile("s_waitcnt vmcnt(0)" ::: "memory");
        BAR();
        RD_B(Brs, cur);
        MFMA16(accR);
    }
#undef SG_A
#undef SG_BK
#undef SG_BV
#undef SG_BR
#undef RD_AALL
#undef RD_B
#undef MFMA16

    const int orow0 = brow + wrow * 64;
    const int ocol0 = bcol + wcol * 32;
    const int rbase = q * 4;
    const int b = brow >> 12;
    float dcol[2][4];
#pragma unroll
    for (int ni = 0; ni < 2; ++ni)
#pragma unroll
        for (int d = 0; d < 4; ++d)
            dcol[ni][d] = dec[b * (D_ * H_) + d * H_ + (ocol0 + ni * 16 + l15)];
#pragma unroll
    for (int mi = 0; mi < 4; ++mi)
#pragma unroll
        for (int j = 0; j < 4; ++j) {
            const int r = orow0 + mi * 16 + rbase + j;
            const f32x4 lw = *(const f32x4*)(lgw + (size_t)r * 4);
            const float wsum = lw[0] + lw[1] + lw[2] + lw[3];
#pragma unroll
            for (int ni = 0; ni < 2; ++ni) {
                const size_t idx = (size_t)r * 1024 + (ocol0 + ni * 16 + l15);
                const float kvf = b2f(f2b(accV[mi][ni][j] * b2f(f2b(accK[mi][ni][j]))));
                const float rv  = 1.0f / (1.0f + __expf(-accR[mi][ni][j]));
                const float w   = lw[0] * dcol[ni][0] + lw[1] * dcol[ni][1]
                                + lw[2] * dcol[ni][2] + lw[3] * dcol[ni][3]
                                + wsum * kvf;
                Co[idx] = f2b(rv * w);
            }
        }
}

// ---------------------------------------------------------------------------
// o-GEMM (R13/R8 structure verbatim, 51us): out = f32(o @ Wo^T)
// 256x256 tile, 8 waves, BK=64, 4 phases, dbuf, swizzle. No XCD remap
// needed: A-sharing blocks (lin stride 64 = 0 mod 8) already co-XCD.
// ---------------------------------------------------------------------------
__global__ __launch_bounds__(512, 2) void gemm_o(
    const unsigned short* __restrict__ A,
    const unsigned short* __restrict__ Wt,
    float* __restrict__ outf)
{
    __shared__ __align__(16) unsigned short As[2 * 256 * 64];
    __shared__ __align__(16) unsigned short Bs[2 * 256 * 64];

    const int tid  = threadIdx.x;
    const int wid  = tid >> 6;
    const int lane = tid & 63;
    const int l15  = lane & 15;
    const int l7   = lane & 7;
    const int wrow = wid >> 2;
    const int wcol = wid & 3;
    const int brow = blockIdx.x * 256;
    const int bcol = blockIdx.y * 256;

    int offA[4], offB[4], dst[4];
#pragma unroll
    for (int i = 0; i < 4; ++i) {
        const int G   = i * 512 + tid;
        const int row = G >> 3;
        const int cg  = (G & 7) ^ (row & 7);
        offA[i] = (brow + row) * 1024 + cg * 8;
        offB[i] = (bcol + row) * 1024 + cg * 8;
        dst[i]  = G * 8;
    }

    int aB[8], bB[4], gx[2];
#pragma unroll
    for (int ks = 0; ks < 2; ++ks) gx[ks] = ((ks * 4 + (lane >> 4)) ^ l7) * 8;
#pragma unroll
    for (int mi = 0; mi < 8; ++mi) aB[mi] = (wrow * 128 + mi * 16 + l15) * 64;
#pragma unroll
    for (int ni = 0; ni < 4; ++ni) bB[ni] = (wcol * 64 + ni * 16 + l15) * 64;

    f32x4 acc[8][4];
#pragma unroll
    for (int i = 0; i < 8; ++i)
#pragma unroll
        for (int j = 0; j < 4; ++j)
            acc[i][j] = (f32x4){0.f, 0.f, 0.f, 0.f};

#pragma unroll
    for (int i = 0; i < 4; ++i) {
        GLLDS(A  + offA[i], As + dst[i]);
        GLLDS(Wt + offB[i], Bs + dst[i]);
    }
    asm volatile("s_waitcnt vmcnt(0)" ::: "memory");
    BAR();

#pragma unroll 1
    for (int t = 0; t < 16; ++t) {
        const int cur = (t & 1) * 16384;
        const int nxt = 16384 - cur;
        const int kk  = (t + 1) * 64;
        const bool st = (t < 15);
        bf16x8 aR[4][2], bR[4][2];

#pragma unroll
        for (int mi = 0; mi < 4; ++mi)
#pragma unroll
            for (int ks = 0; ks < 2; ++ks)
                aR[mi][ks] = *(const bf16x8*)&As[cur + aB[mi] + gx[ks]];
#pragma unroll
        for (int ni = 0; ni < 2; ++ni)
#pragma unroll
            for (int ks = 0; ks < 2; ++ks)
                bR[ni][ks] = *(const bf16x8*)&Bs[cur + bB[ni] + gx[ks]];
        if (st) {
            GLLDS(A  + offA[0] + kk, As + nxt + dst[0]);
            GLLDS(A  + offA[1] + kk, As + nxt + dst[1]);
            GLLDS(Wt + offB[0] + kk, Bs + nxt + dst[0]);
        }
        BAR();
        __builtin_amdgcn_s_setprio(1);
#pragma unroll
        for (int mi = 0; mi < 4; ++mi)
#pragma unroll
            for (int ni = 0; ni < 2; ++ni)
#pragma unroll
                for (int ks = 0; ks < 2; ++ks)
                    acc[mi][ni] = __builtin_amdgcn_mfma_f32_16x16x32_bf16(
                        aR[mi][ks], bR[ni][ks], acc[mi][ni], 0, 0, 0);
        __builtin_amdgcn_s_setprio(0);
        BAR();

#pragma unroll
        for (int ni = 2; ni < 4; ++ni)
#pragma unroll
            for (int ks = 0; ks < 2; ++ks)
                bR[ni][ks] = *(const bf16x8*)&Bs[cur + bB[ni] + gx[ks]];
        if (st) {
            GLLDS(A  + offA[2] + kk, As + nxt + dst[2]);
            GLLDS(A  + offA[3] + kk, As + nxt + dst[3]);
            GLLDS(Wt + offB[1] + kk, Bs + nxt + dst[1]);
        }
        BAR();
        __builtin_amdgcn_s_setprio(1);
#pragma unroll
        for (int mi = 0; mi < 4; ++mi)
#pragma unroll
            for (int ni = 2; ni < 4; ++ni)
#pragma unroll
                for (int ks = 0; ks < 2; ++ks)
                    acc[mi][ni] = __builtin_amdgcn_mfma_f32_16x16x32_bf16(
                        aR[mi][ks], bR[ni][ks], acc[mi][ni], 0, 0, 0);
        __builtin_amdgcn_s_setprio(0);
        BAR();

#pragma unroll
        for (int mi = 0; mi < 4; ++mi)
#pragma unroll
            for (int ks = 0; ks < 2; ++ks)
                aR[mi][ks] = *(const bf16x8*)&As[cur + aB[4 + mi] + gx[ks]];
        if (st) {
            GLLDS(Wt + offB[2] + kk, Bs + nxt + dst[2]);
            GLLDS(Wt + offB[3] + kk, Bs + nxt + dst[3]);
        }
        BAR();
        __builtin_amdgcn_s_setprio(1);
#pragma unroll
        for (int mi = 0; mi < 4; ++mi)
#pragma unroll
            for (int ni = 2; ni < 4; ++ni)
#pragma unroll
                for (int ks = 0; ks < 2; ++ks)
                    acc[4 + mi][ni] = __builtin_amdgcn_mfma_f32_16x16x32_bf16(
                        aR[mi][ks], bR[ni][ks], acc[4 + mi][ni], 0, 0, 0);
        __builtin_amdgcn_s_setprio(0);
        BAR();

        __builtin_amdgcn_s_setprio(1);
#pragma unroll
        for (int mi = 0; mi < 4; ++mi)
#pragma unroll
            for (int ni = 0; ni < 2; ++ni)
#pragma unroll
                for (int ks = 0; ks < 2; ++ks)
                    acc[4 + mi][ni] = __builtin_amdgcn_mfma_f32_16x16x32_bf16(
                        aR[mi][ks], bR[ni][ks], acc[4 + mi][ni], 0, 0, 0);
        __builtin_amdgcn_s_setprio(0);
        asm volatile("s_waitcnt vmcnt(0)" ::: "memory");
        BAR();
    }

    const int orow0 = brow + wrow * 128;
    const int ocol0 = bcol + wcol * 64;
    const int rbase = (lane >> 4) * 4;
#pragma unroll
    for (int mi = 0; mi < 8; ++mi)
#pragma unroll
        for (int j = 0; j < 4; ++j) {
            const size_t r = (size_t)(orow0 + mi * 16 + rbase + j);
#pragma unroll
            for (int ni = 0; ni < 4; ++ni)
                outf[r * 1024 + (ocol0 + ni * 16 + l15)] = acc[mi][ni][j];
        }
}

// ---------------------------------------------------------------------------
extern "C" void kernel_launch(void* const* d_in, const int* in_sizes, int n_in,
                              void* d_out, int out_size, void* d_ws, size_t ws_size,
                              hipStream_t stream)
{
    const float* x   = (const float*)d_in[0];
    const float* st  = (const float*)d_in[1];
    const float* tdm = (const float*)d_in[2];
    const float* Wl  = (const float*)d_in[3];
    const float* bl  = (const float*)d_in[4];
    const float* Wv  = (const float*)d_in[5];
    const float* Wk  = (const float*)d_in[6];
    const float* Wr  = (const float*)d_in[7];
    const float* Wo  = (const float*)d_in[8];
    float* out = (float*)d_out;                    // f32 output

    char* ws = (char*)d_ws;
    unsigned short* buf  = (unsigned short*)(ws + WS_BUF);   // o
    unsigned short* wk_b = (unsigned short*)(ws + WS_WK);    // [4][H][H]: k,v,r,o
    unsigned short* wv_b = wk_b + 1 * (H_ * H_);
    unsigned short* wr_b = wk_b + 2 * (H_ * H_);
    unsigned short* wo_b = wk_b + 3 * (H_ * H_);
    float* lgw = (float*)(ws + WS_LGW);
    float* dec = (float*)(ws + WS_DEC);

    // bf16 x scratch inside d_out's f32 output-0 region; final GEMM
    // fully overwrites it afterwards.
    unsigned short* xb = (unsigned short*)out;

    // small kernels
    decstate_k<<<(B_ * D_ * H_ + 255) / 256, 256, 0, stream>>>(st, tdm, dec);
    logcvt_k<<<M_ / 4, 256, 0, stream>>>(x, Wl, bl, lgw, xb);
    newstate_k<<<(B_ * H_) / 4, 256, 0, stream>>>(x, Wk, Wv, dec, out + OUT_MAIN);
    cvtw_k<<<dim3(1024, 4), 256, 0, stream>>>(Wk, Wv, Wr, Wo, wk_b);

    // buf = o = sigmoid(x@Wr^T) * (lw.dec + wsum*(x@Wk^T * x@Wv^T))
    gemm_kvr<<<dim3(H_ / 128, M_ / 128), 512, 0, stream>>>(
        xb, wk_b, wv_b, wr_b, buf, lgw, dec);

    // out = f32(o @ Wo^T)  [R8 structure — 51us verified]
    gemm_o<<<dim3(M_ / 256, H_ / 256), 512, 0, stream>>>(buf, wo_b, out);
}